// Round 1
// baseline (6090.797 us; speedup 1.0000x reference)
//
#include <hip/hip_runtime.h>
#include <math.h>

#define D 256

// ---------- degree / norm ----------
__global__ void k_init_deg(float* deg, int n) {
    int i = blockIdx.x * 256 + threadIdx.x;
    if (i < n) deg[i] = 1.0f;                 // self-loop
}

__global__ void k_count(const int* __restrict__ row, float* deg, int E) {
    int e = blockIdx.x * 256 + threadIdx.x;
    if (e < E) atomicAdd(&deg[row[e]], 1.0f);
}

__global__ void k_dinv(float* deg, int n) {
    int i = blockIdx.x * 256 + threadIdx.x;
    if (i < n) deg[i] = rsqrtf(deg[i]);       // deg >= 1 always
}

// ---------- GEMM: H[nrows,256] = X[nrows,256] @ W[256,256] ----------
// block = 256 threads, tile = 32 rows x 256 cols
// thread t: col-group cg = t&63 -> cols c0..c0+3 ; row-group rg = t>>6 -> rows r0..r0+7
__global__ __launch_bounds__(256) void k_gemm(const float* __restrict__ X,
                                              const float* __restrict__ W,
                                              float* __restrict__ H, int nrows) {
    __shared__ float As[32][D];
    int t = threadIdx.x;
    int rowBase = blockIdx.x * 32;
    #pragma unroll
    for (int q = 0; q < 32; ++q) {
        int r = rowBase + q;
        As[q][t] = (r < nrows) ? X[(size_t)r * D + t] : 0.0f;
    }
    __syncthreads();

    int cg = t & 63, rg = t >> 6;
    int c0 = cg * 4, r0 = rg * 8;

    float acc[8][4];
    #pragma unroll
    for (int r = 0; r < 8; ++r)
        #pragma unroll
        for (int c = 0; c < 4; ++c) acc[r][c] = 0.0f;

    for (int k = 0; k < D; k += 4) {
        float4 w0 = *(const float4*)&W[(k + 0) * D + c0];
        float4 w1 = *(const float4*)&W[(k + 1) * D + c0];
        float4 w2 = *(const float4*)&W[(k + 2) * D + c0];
        float4 w3 = *(const float4*)&W[(k + 3) * D + c0];
        #pragma unroll
        for (int r = 0; r < 8; ++r) {
            float4 a = *(const float4*)&As[r0 + r][k];
            acc[r][0] = fmaf(a.x, w0.x, fmaf(a.y, w1.x, fmaf(a.z, w2.x, fmaf(a.w, w3.x, acc[r][0]))));
            acc[r][1] = fmaf(a.x, w0.y, fmaf(a.y, w1.y, fmaf(a.z, w2.y, fmaf(a.w, w3.y, acc[r][1]))));
            acc[r][2] = fmaf(a.x, w0.z, fmaf(a.y, w1.z, fmaf(a.z, w2.z, fmaf(a.w, w3.z, acc[r][2]))));
            acc[r][3] = fmaf(a.x, w0.w, fmaf(a.y, w1.w, fmaf(a.z, w2.w, fmaf(a.w, w3.w, acc[r][3]))));
        }
    }
    #pragma unroll
    for (int r = 0; r < 8; ++r) {
        int rr = rowBase + r0 + r;
        if (rr < nrows) {
            float4 o = make_float4(acc[r][0], acc[r][1], acc[r][2], acc[r][3]);
            *(float4*)&H[(size_t)rr * D + c0] = o;
        }
    }
}

// ---------- aggregate: init with self-loop + bias ----------
__global__ void k_agg_init(const float* __restrict__ Hh, const float* __restrict__ dinv,
                           const float* __restrict__ b, float* __restrict__ Xo, int n) {
    int idx = blockIdx.x * 256 + threadIdx.x;   // one float4 each
    if (idx >= n * (D / 4)) return;
    int r = idx >> 6;
    int c4 = (idx & 63) * 4;
    float s = dinv[r]; s = s * s;
    float4 h = *(const float4*)&Hh[(size_t)r * D + c4];
    float4 bb = *(const float4*)&b[c4];
    float4 o = make_float4(fmaf(h.x, s, bb.x), fmaf(h.y, s, bb.y),
                           fmaf(h.z, s, bb.z), fmaf(h.w, s, bb.w));
    *(float4*)&Xo[(size_t)r * D + c4] = o;
}

// ---------- aggregate: edge scatter (one wave per edge) ----------
__global__ __launch_bounds__(256) void k_scatter(const int* __restrict__ row, const int* __restrict__ col,
                                                 const float* __restrict__ Hh, const float* __restrict__ dinv,
                                                 float* __restrict__ Xo, int E) {
    int e = blockIdx.x * 4 + (threadIdx.x >> 6);
    if (e >= E) return;
    int lane = threadIdx.x & 63;
    int r = row[e], c = col[e];
    float nrm = dinv[r] * dinv[c];
    float4 h = *(const float4*)&Hh[(size_t)c * D + lane * 4];
    float* dst = &Xo[(size_t)r * D + lane * 4];
    atomicAdd(dst + 0, h.x * nrm);
    atomicAdd(dst + 1, h.y * nrm);
    atomicAdd(dst + 2, h.z * nrm);
    atomicAdd(dst + 3, h.w * nrm);
}

__global__ void k_relu(float* x, int total4) {
    int idx = blockIdx.x * 256 + threadIdx.x;
    if (idx >= total4) return;
    float4 v = *(float4*)&x[(size_t)idx * 4];
    v.x = fmaxf(v.x, 0.f); v.y = fmaxf(v.y, 0.f);
    v.z = fmaxf(v.z, 0.f); v.w = fmaxf(v.w, 0.f);
    *(float4*)&x[(size_t)idx * 4] = v;
}

// ---------- link predictor: 32 queries/block ----------
__global__ __launch_bounds__(256) void k_linkpred(const int* __restrict__ u, const int* __restrict__ v,
                                                  const float* __restrict__ X,
                                                  const float* __restrict__ P1w, const float* __restrict__ P1b,
                                                  const float* __restrict__ P2w, const float* __restrict__ P2b,
                                                  float* __restrict__ out, int Q) {
    __shared__ float As[32][D];
    int t = threadIdx.x;
    int q0 = blockIdx.x * 32;
    #pragma unroll
    for (int q = 0; q < 32; ++q) {
        int qq = q0 + q;
        float val = 0.f;
        if (qq < Q) {
            int a = u[qq], b = v[qq];
            val = X[(size_t)a * D + t] * X[(size_t)b * D + t];
        }
        As[q][t] = val;
    }
    __syncthreads();

    int cg = t & 63, rg = t >> 6;
    int c0 = cg * 4, r0 = rg * 8;

    float4 b1v = *(const float4*)&P1b[c0];
    float acc[8][4];
    #pragma unroll
    for (int r = 0; r < 8; ++r) {
        acc[r][0] = b1v.x; acc[r][1] = b1v.y; acc[r][2] = b1v.z; acc[r][3] = b1v.w;
    }

    for (int k = 0; k < D; k += 4) {
        float4 w0 = *(const float4*)&P1w[(k + 0) * D + c0];
        float4 w1 = *(const float4*)&P1w[(k + 1) * D + c0];
        float4 w2 = *(const float4*)&P1w[(k + 2) * D + c0];
        float4 w3 = *(const float4*)&P1w[(k + 3) * D + c0];
        #pragma unroll
        for (int r = 0; r < 8; ++r) {
            float4 a = *(const float4*)&As[r0 + r][k];
            acc[r][0] = fmaf(a.x, w0.x, fmaf(a.y, w1.x, fmaf(a.z, w2.x, fmaf(a.w, w3.x, acc[r][0]))));
            acc[r][1] = fmaf(a.x, w0.y, fmaf(a.y, w1.y, fmaf(a.z, w2.y, fmaf(a.w, w3.y, acc[r][1]))));
            acc[r][2] = fmaf(a.x, w0.z, fmaf(a.y, w1.z, fmaf(a.z, w2.z, fmaf(a.w, w3.z, acc[r][2]))));
            acc[r][3] = fmaf(a.x, w0.w, fmaf(a.y, w1.w, fmaf(a.z, w2.w, fmaf(a.w, w3.w, acc[r][3]))));
        }
    }

    // layer 2: relu(acc) . P2w  -> per-thread partial over its 4 cols, shuffle-reduce over
    // the 64 col-groups (which are exactly one wave: lanes = cg)
    float4 p2 = *(const float4*)&P2w[c0];
    float p2b = P2b[0];
    #pragma unroll
    for (int r = 0; r < 8; ++r) {
        float s = fmaxf(acc[r][0], 0.f) * p2.x + fmaxf(acc[r][1], 0.f) * p2.y +
                  fmaxf(acc[r][2], 0.f) * p2.z + fmaxf(acc[r][3], 0.f) * p2.w;
        s += __shfl_down(s, 32);
        s += __shfl_down(s, 16);
        s += __shfl_down(s, 8);
        s += __shfl_down(s, 4);
        s += __shfl_down(s, 2);
        s += __shfl_down(s, 1);
        if (cg == 0) {
            int qq = q0 + r0 + r;
            if (qq < Q) out[qq] = 1.0f / (1.0f + expf(-(s + p2b)));
        }
    }
}

extern "C" void kernel_launch(void* const* d_in, const int* in_sizes, int n_in,
                              void* d_out, int out_size, void* d_ws, size_t ws_size,
                              hipStream_t stream) {
    const int*   edge_index = (const int*)d_in[0];
    const int*   edges      = (const int*)d_in[1];
    const float* emb        = (const float*)d_in[2];
    const float* W1         = (const float*)d_in[3];
    const float* b1         = (const float*)d_in[4];
    const float* W2         = (const float*)d_in[5];
    const float* b2         = (const float*)d_in[6];
    const float* P1w        = (const float*)d_in[7];
    const float* P1b        = (const float*)d_in[8];
    const float* P2w        = (const float*)d_in[9];
    const float* P2b        = (const float*)d_in[10];

    int E  = in_sizes[0] / 2;
    int Q  = in_sizes[1] / 2;
    int Nn = in_sizes[2] / D;

    const int* rowp = edge_index;
    const int* colp = edge_index + E;
    const int* uq   = edges;
    const int* vq   = edges + Q;
    float* out = (float*)d_out;

    char* ws = (char*)d_ws;
    float* dinv = (float*)ws;
    size_t off = (((size_t)Nn * 4) + 255) & ~(size_t)255;
    float* hbuf = (float*)(ws + off);
    size_t hbytes = (size_t)Nn * D * sizeof(float);
    float* xbuf = (float*)(ws + off + hbytes);

    int nb;
    // degree -> dinv
    nb = (Nn + 255) / 256; k_init_deg<<<nb, 256, 0, stream>>>(dinv, Nn);
    nb = (E + 255) / 256;  k_count<<<nb, 256, 0, stream>>>(rowp, dinv, E);
    nb = (Nn + 255) / 256; k_dinv<<<nb, 256, 0, stream>>>(dinv, Nn);

    // conv1: h = emb @ W1 ; x1 = relu(D^-1/2 A D^-1/2 h + b1)
    nb = (Nn + 31) / 32;        k_gemm<<<nb, 256, 0, stream>>>(emb, W1, hbuf, Nn);
    nb = (Nn * 64 + 255) / 256; k_agg_init<<<nb, 256, 0, stream>>>(hbuf, dinv, b1, xbuf, Nn);
    nb = (E + 3) / 4;           k_scatter<<<nb, 256, 0, stream>>>(rowp, colp, hbuf, dinv, xbuf, E);
    nb = (Nn * 64 + 255) / 256; k_relu<<<nb, 256, 0, stream>>>(xbuf, Nn * 64);

    // conv2: h = x1 @ W2 ; x2 = D^-1/2 A D^-1/2 h + b2
    nb = (Nn + 31) / 32;        k_gemm<<<nb, 256, 0, stream>>>(xbuf, W2, hbuf, Nn);
    nb = (Nn * 64 + 255) / 256; k_agg_init<<<nb, 256, 0, stream>>>(hbuf, dinv, b2, xbuf, Nn);
    nb = (E + 3) / 4;           k_scatter<<<nb, 256, 0, stream>>>(rowp, colp, hbuf, dinv, xbuf, E);

    // link predictor
    nb = (Q + 31) / 32;         k_linkpred<<<nb, 256, 0, stream>>>(uq, vq, xbuf, P1w, P1b, P2w, P2b, out, Q);
}

// Round 3
// 960.550 us; speedup vs baseline: 6.3410x; 6.3410x over previous
//
#include <hip/hip_runtime.h>
#include <math.h>

#define D 256
#define SCAN_CHUNK 1024

// ---------- zero int buffer ----------
__global__ void k_zero_int(int* p, int n) {
    int i = blockIdx.x * 256 + threadIdx.x;
    if (i < n) p[i] = 0;
}

// ---------- int degree count (edges only; self-loop added later) ----------
__global__ void k_count_int(const int* __restrict__ row, int* deg, int E) {
    int e = blockIdx.x * 256 + threadIdx.x;
    if (e < E) atomicAdd(&deg[row[e]], 1);
}

// ---------- prefix scan (3 stages); excl written into rowptr ----------
__global__ __launch_bounds__(256) void k_scan_block(const int* __restrict__ deg, int* __restrict__ excl,
                                                    int* __restrict__ bsums, int n) {
    __shared__ int s[256];
    int blk = blockIdx.x, t = threadIdx.x;
    int base = blk * SCAN_CHUNK + t * 4;
    int v0 = (base + 0 < n) ? deg[base + 0] : 0;
    int v1 = (base + 1 < n) ? deg[base + 1] : 0;
    int v2 = (base + 2 < n) ? deg[base + 2] : 0;
    int v3 = (base + 3 < n) ? deg[base + 3] : 0;
    int tsum = v0 + v1 + v2 + v3;
    s[t] = tsum;
    __syncthreads();
    for (int off = 1; off < 256; off <<= 1) {
        int x = (t >= off) ? s[t - off] : 0;
        __syncthreads();
        s[t] += x;
        __syncthreads();
    }
    int run = s[t] - tsum;  // exclusive prefix of this thread within block
    if (t == 255) bsums[blk] = s[255];
    if (base + 0 < n) excl[base + 0] = run;
    run += v0;
    if (base + 1 < n) excl[base + 1] = run;
    run += v1;
    if (base + 2 < n) excl[base + 2] = run;
    run += v2;
    if (base + 3 < n) excl[base + 3] = run;
}

__global__ __launch_bounds__(256) void k_scan_bsums(int* bsums, int nb) {
    __shared__ int s[256];
    int t = threadIdx.x;
    int v = (t < nb) ? bsums[t] : 0;
    s[t] = v;
    __syncthreads();
    for (int off = 1; off < 256; off <<= 1) {
        int x = (t >= off) ? s[t - off] : 0;
        __syncthreads();
        s[t] += x;
        __syncthreads();
    }
    if (t < nb) bsums[t] = s[t] - v;  // exclusive
}

// in-place: rowptr[i] += bsums[i/SCAN_CHUNK]
__global__ void k_scan_add(int* __restrict__ rowptr, const int* __restrict__ bsums, int n, int total) {
    int i = blockIdx.x * 256 + threadIdx.x;
    if (i < n) rowptr[i] += bsums[i / SCAN_CHUNK];
    if (i == 0) rowptr[n] = total;
}

// ---------- dinv = (deg+1)^-1/2 ----------
__global__ void k_dinv(const int* __restrict__ deg, float* __restrict__ dinv, int n) {
    int i = blockIdx.x * 256 + threadIdx.x;
    if (i < n) dinv[i] = rsqrtf((float)(deg[i] + 1));
}

// ---------- bucket edges into CSR ----------
__global__ void k_bucket(const int* __restrict__ row, const int* __restrict__ col,
                         const int* __restrict__ rowptr, int* __restrict__ fill,
                         int* __restrict__ ebuf, int E) {
    int e = blockIdx.x * 256 + threadIdx.x;
    if (e >= E) return;
    int r = row[e];
    int pos = atomicAdd(&fill[r], 1);
    ebuf[rowptr[r] + pos] = col[e];
}

// ---------- GEMM: H[nrows,256] = X[nrows,256] @ W[256,256] ----------
__global__ __launch_bounds__(256) void k_gemm(const float* __restrict__ X,
                                              const float* __restrict__ W,
                                              float* __restrict__ H, int nrows) {
    __shared__ float As[32][D];
    int t = threadIdx.x;
    int rowBase = blockIdx.x * 32;
    #pragma unroll
    for (int q = 0; q < 32; ++q) {
        int r = rowBase + q;
        As[q][t] = (r < nrows) ? X[(size_t)r * D + t] : 0.0f;
    }
    __syncthreads();

    int cg = t & 63, rg = t >> 6;
    int c0 = cg * 4, r0 = rg * 8;

    float acc[8][4];
    #pragma unroll
    for (int r = 0; r < 8; ++r)
        #pragma unroll
        for (int c = 0; c < 4; ++c) acc[r][c] = 0.0f;

    for (int k = 0; k < D; k += 4) {
        float4 w0 = *(const float4*)&W[(k + 0) * D + c0];
        float4 w1 = *(const float4*)&W[(k + 1) * D + c0];
        float4 w2 = *(const float4*)&W[(k + 2) * D + c0];
        float4 w3 = *(const float4*)&W[(k + 3) * D + c0];
        #pragma unroll
        for (int r = 0; r < 8; ++r) {
            float4 a = *(const float4*)&As[r0 + r][k];
            acc[r][0] = fmaf(a.x, w0.x, fmaf(a.y, w1.x, fmaf(a.z, w2.x, fmaf(a.w, w3.x, acc[r][0]))));
            acc[r][1] = fmaf(a.x, w0.y, fmaf(a.y, w1.y, fmaf(a.z, w2.y, fmaf(a.w, w3.y, acc[r][1]))));
            acc[r][2] = fmaf(a.x, w0.z, fmaf(a.y, w1.z, fmaf(a.z, w2.z, fmaf(a.w, w3.z, acc[r][2]))));
            acc[r][3] = fmaf(a.x, w0.w, fmaf(a.y, w1.w, fmaf(a.z, w2.w, fmaf(a.w, w3.w, acc[r][3]))));
        }
    }
    #pragma unroll
    for (int r = 0; r < 8; ++r) {
        int rr = rowBase + r0 + r;
        if (rr < nrows) {
            float4 o = make_float4(acc[r][0], acc[r][1], acc[r][2], acc[r][3]);
            *(float4*)&H[(size_t)rr * D + c0] = o;
        }
    }
}

// ---------- aggregate by gather: one wave per destination node ----------
__global__ __launch_bounds__(256) void k_agg(const float* __restrict__ Hh,
                                             const int* __restrict__ rowptr, const int* __restrict__ ebuf,
                                             const float* __restrict__ dinv, const float* __restrict__ b,
                                             float* __restrict__ Xo, int n, int relu) {
    int node = blockIdx.x * 4 + (threadIdx.x >> 6);
    if (node >= n) return;
    int lane = threadIdx.x & 63;
    int c4 = lane * 4;

    float dn = dinv[node];
    float self = dn * dn;
    float4 h = *(const float4*)&Hh[(size_t)node * D + c4];
    float4 bb = *(const float4*)&b[c4];
    float4 acc = make_float4(fmaf(h.x, self, bb.x), fmaf(h.y, self, bb.y),
                             fmaf(h.z, self, bb.z), fmaf(h.w, self, bb.w));

    int beg = rowptr[node], end = rowptr[node + 1];
    int j = beg;
    for (; j + 1 < end; j += 2) {
        int cA = ebuf[j], cB = ebuf[j + 1];
        float nA = dn * dinv[cA], nB = dn * dinv[cB];
        float4 hA = *(const float4*)&Hh[(size_t)cA * D + c4];
        float4 hB = *(const float4*)&Hh[(size_t)cB * D + c4];
        acc.x = fmaf(hA.x, nA, acc.x); acc.y = fmaf(hA.y, nA, acc.y);
        acc.z = fmaf(hA.z, nA, acc.z); acc.w = fmaf(hA.w, nA, acc.w);
        acc.x = fmaf(hB.x, nB, acc.x); acc.y = fmaf(hB.y, nB, acc.y);
        acc.z = fmaf(hB.z, nB, acc.z); acc.w = fmaf(hB.w, nB, acc.w);
    }
    if (j < end) {
        int cA = ebuf[j];
        float nA = dn * dinv[cA];
        float4 hA = *(const float4*)&Hh[(size_t)cA * D + c4];
        acc.x = fmaf(hA.x, nA, acc.x); acc.y = fmaf(hA.y, nA, acc.y);
        acc.z = fmaf(hA.z, nA, acc.z); acc.w = fmaf(hA.w, nA, acc.w);
    }
    if (relu) {
        acc.x = fmaxf(acc.x, 0.f); acc.y = fmaxf(acc.y, 0.f);
        acc.z = fmaxf(acc.z, 0.f); acc.w = fmaxf(acc.w, 0.f);
    }
    *(float4*)&Xo[(size_t)node * D + c4] = acc;
}

// ---------- link predictor: 32 queries/block ----------
__global__ __launch_bounds__(256) void k_linkpred(const int* __restrict__ u, const int* __restrict__ v,
                                                  const float* __restrict__ X,
                                                  const float* __restrict__ P1w, const float* __restrict__ P1b,
                                                  const float* __restrict__ P2w, const float* __restrict__ P2b,
                                                  float* __restrict__ out, int Q) {
    __shared__ float As[32][D];
    int t = threadIdx.x;
    int q0 = blockIdx.x * 32;
    #pragma unroll
    for (int q = 0; q < 32; ++q) {
        int qq = q0 + q;
        float val = 0.f;
        if (qq < Q) {
            int a = u[qq], b = v[qq];
            val = X[(size_t)a * D + t] * X[(size_t)b * D + t];
        }
        As[q][t] = val;
    }
    __syncthreads();

    int cg = t & 63, rg = t >> 6;
    int c0 = cg * 4, r0 = rg * 8;

    float4 b1v = *(const float4*)&P1b[c0];
    float acc[8][4];
    #pragma unroll
    for (int r = 0; r < 8; ++r) {
        acc[r][0] = b1v.x; acc[r][1] = b1v.y; acc[r][2] = b1v.z; acc[r][3] = b1v.w;
    }

    for (int k = 0; k < D; k += 4) {
        float4 w0 = *(const float4*)&P1w[(k + 0) * D + c0];
        float4 w1 = *(const float4*)&P1w[(k + 1) * D + c0];
        float4 w2 = *(const float4*)&P1w[(k + 2) * D + c0];
        float4 w3 = *(const float4*)&P1w[(k + 3) * D + c0];
        #pragma unroll
        for (int r = 0; r < 8; ++r) {
            float4 a = *(const float4*)&As[r0 + r][k];
            acc[r][0] = fmaf(a.x, w0.x, fmaf(a.y, w1.x, fmaf(a.z, w2.x, fmaf(a.w, w3.x, acc[r][0]))));
            acc[r][1] = fmaf(a.x, w0.y, fmaf(a.y, w1.y, fmaf(a.z, w2.y, fmaf(a.w, w3.y, acc[r][1]))));
            acc[r][2] = fmaf(a.x, w0.z, fmaf(a.y, w1.z, fmaf(a.z, w2.z, fmaf(a.w, w3.z, acc[r][2]))));
            acc[r][3] = fmaf(a.x, w0.w, fmaf(a.y, w1.w, fmaf(a.z, w2.w, fmaf(a.w, w3.w, acc[r][3]))));
        }
    }

    float4 p2 = *(const float4*)&P2w[c0];
    float p2b = P2b[0];
    #pragma unroll
    for (int r = 0; r < 8; ++r) {
        float s = fmaxf(acc[r][0], 0.f) * p2.x + fmaxf(acc[r][1], 0.f) * p2.y +
                  fmaxf(acc[r][2], 0.f) * p2.z + fmaxf(acc[r][3], 0.f) * p2.w;
        s += __shfl_down(s, 32);
        s += __shfl_down(s, 16);
        s += __shfl_down(s, 8);
        s += __shfl_down(s, 4);
        s += __shfl_down(s, 2);
        s += __shfl_down(s, 1);
        if (cg == 0) {
            int qq = q0 + r0 + r;
            if (qq < Q) out[qq] = 1.0f / (1.0f + expf(-(s + p2b)));
        }
    }
}

extern "C" void kernel_launch(void* const* d_in, const int* in_sizes, int n_in,
                              void* d_out, int out_size, void* d_ws, size_t ws_size,
                              hipStream_t stream) {
    const int*   edge_index = (const int*)d_in[0];
    const int*   edges      = (const int*)d_in[1];
    const float* emb        = (const float*)d_in[2];
    const float* W1         = (const float*)d_in[3];
    const float* b1         = (const float*)d_in[4];
    const float* W2         = (const float*)d_in[5];
    const float* b2         = (const float*)d_in[6];
    const float* P1w        = (const float*)d_in[7];
    const float* P1b        = (const float*)d_in[8];
    const float* P2w        = (const float*)d_in[9];
    const float* P2b        = (const float*)d_in[10];

    int E  = in_sizes[0] / 2;
    int Q  = in_sizes[1] / 2;
    int Nn = in_sizes[2] / D;

    const int* rowp = edge_index;
    const int* colp = edge_index + E;
    const int* uq   = edges;
    const int* vq   = edges + Q;
    float* out = (float*)d_out;

    // ---- workspace layout (persistent regions) ----
    char* ws = (char*)d_ws;
    size_t off = 0;
    auto alloc = [&](size_t bytes) -> char* {
        char* p = ws + off;
        off = (off + bytes + 255) & ~(size_t)255;
        return p;
    };
    float* dinv   = (float*)alloc((size_t)Nn * 4);
    int*   rowptr = (int*)  alloc(((size_t)Nn + 1) * 4);
    int*   ebuf   = (int*)  alloc((size_t)E * 4);
    float* hbuf   = (float*)alloc((size_t)Nn * D * 4);
    float* xbuf   = (float*)alloc((size_t)Nn * D * 4);

    // ---- CSR-build temporaries aliased into xbuf (xbuf unwritten until k_agg) ----
    // degi and fill are CONTIGUOUS (no padding) so one zero-fill covers both.
    int* degi  = (int*)xbuf;
    int* fill  = degi + Nn;          // contiguous with degi
    int* bsums = degi + 2 * Nn;      // after fill

    int nb;
    int nscan = (Nn + SCAN_CHUNK - 1) / SCAN_CHUNK;

    // CSR build
    nb = (2 * Nn + 255) / 256; k_zero_int<<<nb, 256, 0, stream>>>(degi, 2 * Nn);
    nb = (E + 255) / 256;      k_count_int<<<nb, 256, 0, stream>>>(rowp, degi, E);
    k_scan_block<<<nscan, 256, 0, stream>>>(degi, rowptr, bsums, Nn);
    k_scan_bsums<<<1, 256, 0, stream>>>(bsums, nscan);
    nb = (Nn + 255) / 256;     k_scan_add<<<nb, 256, 0, stream>>>(rowptr, bsums, Nn, E);
    nb = (Nn + 255) / 256;     k_dinv<<<nb, 256, 0, stream>>>(degi, dinv, Nn);
    nb = (E + 255) / 256;      k_bucket<<<nb, 256, 0, stream>>>(rowp, colp, rowptr, fill, ebuf, E);

    // conv1: h = emb @ W1 ; x1 = relu(D^-1/2 (A+I) D^-1/2 h + b1)
    nb = (Nn + 31) / 32; k_gemm<<<nb, 256, 0, stream>>>(emb, W1, hbuf, Nn);
    nb = (Nn + 3) / 4;   k_agg<<<nb, 256, 0, stream>>>(hbuf, rowptr, ebuf, dinv, b1, xbuf, Nn, 1);

    // conv2
    nb = (Nn + 31) / 32; k_gemm<<<nb, 256, 0, stream>>>(xbuf, W2, hbuf, Nn);
    nb = (Nn + 3) / 4;   k_agg<<<nb, 256, 0, stream>>>(hbuf, rowptr, ebuf, dinv, b2, xbuf, Nn, 0);

    // link predictor
    nb = (Q + 31) / 32;  k_linkpred<<<nb, 256, 0, stream>>>(uq, vq, xbuf, P1w, P1b, P2w, P2b, out, Q);
}

// Round 4
// 722.831 us; speedup vs baseline: 8.4263x; 1.3289x over previous
//
#include <hip/hip_runtime.h>
#include <math.h>

#define D 256
#define SCAN_CHUNK 1024

typedef __attribute__((ext_vector_type(8))) short frag_ab;   // 8 bf16
typedef __attribute__((ext_vector_type(4))) float frag_cd;   // 4 fp32

__device__ inline unsigned short f2b(float f) {
    unsigned int u = __float_as_uint(f);
    u += 0x7fffu + ((u >> 16) & 1u);
    return (unsigned short)(u >> 16);
}
__device__ inline float b2f(unsigned short h) {
    return __uint_as_float(((unsigned int)h) << 16);
}

// ---------- zero int buffer ----------
__global__ void k_zero_int(int* p, int n) {
    int i = blockIdx.x * 256 + threadIdx.x;
    if (i < n) p[i] = 0;
}

// ---------- int degree count ----------
__global__ void k_count_int(const int* __restrict__ row, int* deg, int E) {
    int e = blockIdx.x * 256 + threadIdx.x;
    if (e < E) atomicAdd(&deg[row[e]], 1);
}

// ---------- prefix scan (3 stages); excl written into rowptr ----------
__global__ __launch_bounds__(256) void k_scan_block(const int* __restrict__ deg, int* __restrict__ excl,
                                                    int* __restrict__ bsums, int n) {
    __shared__ int s[256];
    int blk = blockIdx.x, t = threadIdx.x;
    int base = blk * SCAN_CHUNK + t * 4;
    int v0 = (base + 0 < n) ? deg[base + 0] : 0;
    int v1 = (base + 1 < n) ? deg[base + 1] : 0;
    int v2 = (base + 2 < n) ? deg[base + 2] : 0;
    int v3 = (base + 3 < n) ? deg[base + 3] : 0;
    int tsum = v0 + v1 + v2 + v3;
    s[t] = tsum;
    __syncthreads();
    for (int off = 1; off < 256; off <<= 1) {
        int x = (t >= off) ? s[t - off] : 0;
        __syncthreads();
        s[t] += x;
        __syncthreads();
    }
    int run = s[t] - tsum;
    if (t == 255) bsums[blk] = s[255];
    if (base + 0 < n) excl[base + 0] = run;
    run += v0;
    if (base + 1 < n) excl[base + 1] = run;
    run += v1;
    if (base + 2 < n) excl[base + 2] = run;
    run += v2;
    if (base + 3 < n) excl[base + 3] = run;
}

__global__ __launch_bounds__(256) void k_scan_bsums(int* bsums, int nb) {
    __shared__ int s[256];
    int t = threadIdx.x;
    int v = (t < nb) ? bsums[t] : 0;
    s[t] = v;
    __syncthreads();
    for (int off = 1; off < 256; off <<= 1) {
        int x = (t >= off) ? s[t - off] : 0;
        __syncthreads();
        s[t] += x;
        __syncthreads();
    }
    if (t < nb) bsums[t] = s[t] - v;
}

__global__ void k_scan_add(int* __restrict__ rowptr, const int* __restrict__ bsums, int n, int total) {
    int i = blockIdx.x * 256 + threadIdx.x;
    if (i < n) rowptr[i] += bsums[i / SCAN_CHUNK];
    if (i == 0) rowptr[n] = total;
}

// ---------- dinv = (deg+1)^-1/2 ----------
__global__ void k_dinv(const int* __restrict__ deg, float* __restrict__ dinv, int n) {
    int i = blockIdx.x * 256 + threadIdx.x;
    if (i < n) dinv[i] = rsqrtf((float)(deg[i] + 1));
}

// ---------- bucket edges into CSR ----------
__global__ void k_bucket(const int* __restrict__ row, const int* __restrict__ col,
                         const int* __restrict__ rowptr, int* __restrict__ fill,
                         int* __restrict__ ebuf, int E) {
    int e = blockIdx.x * 256 + threadIdx.x;
    if (e >= E) return;
    int r = row[e];
    int pos = atomicAdd(&fill[r], 1);
    ebuf[rowptr[r] + pos] = col[e];
}

// ---------- pack P1w (fp32 [k][n]) into MFMA B-fragment order (bf16) ----------
// frag f = (ntile*8 + kt)*64 + lane ; element j -> B[k = kt*32 + (lane>>4)*8 + j][n = ntile*16 + (lane&15)]
__global__ void k_packB(const float* __restrict__ W, unsigned short* __restrict__ Bp) {
    int i = blockIdx.x * 256 + threadIdx.x;   // 65536 total
    int ntile = i >> 12;
    int kt = (i >> 9) & 7;
    int lane = (i >> 3) & 63;
    int j = i & 7;
    int k = kt * 32 + (lane >> 4) * 8 + j;
    int n = ntile * 16 + (lane & 15);
    Bp[i] = f2b(W[k * D + n]);
}

// ---------- GEMM: H[nrows,256] = X[nrows,256] @ W[256,256] (fp32) ----------
__global__ __launch_bounds__(256) void k_gemm(const float* __restrict__ X,
                                              const float* __restrict__ W,
                                              float* __restrict__ H, int nrows) {
    __shared__ float As[32][D];
    int t = threadIdx.x;
    int rowBase = blockIdx.x * 32;
    #pragma unroll
    for (int q = 0; q < 32; ++q) {
        int r = rowBase + q;
        As[q][t] = (r < nrows) ? X[(size_t)r * D + t] : 0.0f;
    }
    __syncthreads();

    int cg = t & 63, rg = t >> 6;
    int c0 = cg * 4, r0 = rg * 8;

    float acc[8][4];
    #pragma unroll
    for (int r = 0; r < 8; ++r)
        #pragma unroll
        for (int c = 0; c < 4; ++c) acc[r][c] = 0.0f;

    for (int k = 0; k < D; k += 4) {
        float4 w0 = *(const float4*)&W[(k + 0) * D + c0];
        float4 w1 = *(const float4*)&W[(k + 1) * D + c0];
        float4 w2 = *(const float4*)&W[(k + 2) * D + c0];
        float4 w3 = *(const float4*)&W[(k + 3) * D + c0];
        #pragma unroll
        for (int r = 0; r < 8; ++r) {
            float4 a = *(const float4*)&As[r0 + r][k];
            acc[r][0] = fmaf(a.x, w0.x, fmaf(a.y, w1.x, fmaf(a.z, w2.x, fmaf(a.w, w3.x, acc[r][0]))));
            acc[r][1] = fmaf(a.x, w0.y, fmaf(a.y, w1.y, fmaf(a.z, w2.y, fmaf(a.w, w3.y, acc[r][1]))));
            acc[r][2] = fmaf(a.x, w0.z, fmaf(a.y, w1.z, fmaf(a.z, w2.z, fmaf(a.w, w3.z, acc[r][2]))));
            acc[r][3] = fmaf(a.x, w0.w, fmaf(a.y, w1.w, fmaf(a.z, w2.w, fmaf(a.w, w3.w, acc[r][3]))));
        }
    }
    #pragma unroll
    for (int r = 0; r < 8; ++r) {
        int rr = rowBase + r0 + r;
        if (rr < nrows) {
            float4 o = make_float4(acc[r][0], acc[r][1], acc[r][2], acc[r][3]);
            *(float4*)&H[(size_t)rr * D + c0] = o;
        }
    }
}

// ---------- aggregate by gather: one wave per destination node ----------
// mode 1: relu, fp32 out.   mode 2: no relu, bf16 out (for link predictor).
__global__ __launch_bounds__(256) void k_agg(const float* __restrict__ Hh,
                                             const int* __restrict__ rowptr, const int* __restrict__ ebuf,
                                             const float* __restrict__ dinv, const float* __restrict__ b,
                                             void* __restrict__ Xo, int n, int mode) {
    int node = blockIdx.x * 4 + (threadIdx.x >> 6);
    if (node >= n) return;
    int lane = threadIdx.x & 63;
    int c4 = lane * 4;

    float dn = dinv[node];
    float self = dn * dn;
    float4 h = *(const float4*)&Hh[(size_t)node * D + c4];
    float4 bb = *(const float4*)&b[c4];
    float4 acc = make_float4(fmaf(h.x, self, bb.x), fmaf(h.y, self, bb.y),
                             fmaf(h.z, self, bb.z), fmaf(h.w, self, bb.w));

    int beg = rowptr[node], end = rowptr[node + 1];
    int j = beg;
    for (; j + 1 < end; j += 2) {
        int cA = ebuf[j], cB = ebuf[j + 1];
        float nA = dn * dinv[cA], nB = dn * dinv[cB];
        float4 hA = *(const float4*)&Hh[(size_t)cA * D + c4];
        float4 hB = *(const float4*)&Hh[(size_t)cB * D + c4];
        acc.x = fmaf(hA.x, nA, acc.x); acc.y = fmaf(hA.y, nA, acc.y);
        acc.z = fmaf(hA.z, nA, acc.z); acc.w = fmaf(hA.w, nA, acc.w);
        acc.x = fmaf(hB.x, nB, acc.x); acc.y = fmaf(hB.y, nB, acc.y);
        acc.z = fmaf(hB.z, nB, acc.z); acc.w = fmaf(hB.w, nB, acc.w);
    }
    if (j < end) {
        int cA = ebuf[j];
        float nA = dn * dinv[cA];
        float4 hA = *(const float4*)&Hh[(size_t)cA * D + c4];
        acc.x = fmaf(hA.x, nA, acc.x); acc.y = fmaf(hA.y, nA, acc.y);
        acc.z = fmaf(hA.z, nA, acc.z); acc.w = fmaf(hA.w, nA, acc.w);
    }
    if (mode == 1) {
        acc.x = fmaxf(acc.x, 0.f); acc.y = fmaxf(acc.y, 0.f);
        acc.z = fmaxf(acc.z, 0.f); acc.w = fmaxf(acc.w, 0.f);
        *(float4*)((float*)Xo + (size_t)node * D + c4) = acc;
    } else {
        unsigned long long pk = (unsigned long long)f2b(acc.x)
                              | ((unsigned long long)f2b(acc.y) << 16)
                              | ((unsigned long long)f2b(acc.z) << 32)
                              | ((unsigned long long)f2b(acc.w) << 48);
        *(unsigned long long*)((unsigned short*)Xo + (size_t)node * D + c4) = pk;
    }
}

// ---------- link predictor: 32 queries/block, MFMA bf16 ----------
// LDS G: 32 rows x 264 bf16 (pad 8 to break ds_read_b128 bank conflicts)
#define GPITCH 264
__global__ __launch_bounds__(256) void k_linkpred(const int* __restrict__ u, const int* __restrict__ v,
                                                  const unsigned short* __restrict__ X16,
                                                  const unsigned short* __restrict__ Bpack,
                                                  const float* __restrict__ P1b,
                                                  const float* __restrict__ P2w, const float* __restrict__ P2b,
                                                  float* __restrict__ out, int Q) {
    __shared__ unsigned short Gs[32 * GPITCH];
    __shared__ float red[2][32];

    int t = threadIdx.x;
    int q0 = blockIdx.x * 32;

    // ---- stage 1: gather endpoint rows, elementwise product, store bf16 to LDS ----
    {
        int half = t >> 7;         // 0/1: which query of the pair
        int cpair = t & 127;       // uint (2 bf16) index within a 256-col row
        for (int qi = 0; qi < 32; qi += 2) {
            int q = qi + half;
            int qq = q0 + q;
            unsigned int val = 0;
            if (qq < Q) {
                const unsigned int* ru = (const unsigned int*)(X16 + (size_t)u[qq] * D);
                const unsigned int* rv = (const unsigned int*)(X16 + (size_t)v[qq] * D);
                unsigned int a = ru[cpair], b = rv[cpair];
                float p0 = b2f((unsigned short)(a & 0xffffu)) * b2f((unsigned short)(b & 0xffffu));
                float p1 = b2f((unsigned short)(a >> 16))     * b2f((unsigned short)(b >> 16));
                val = (unsigned int)f2b(p0) | ((unsigned int)f2b(p1) << 16);
            }
            *(unsigned int*)&Gs[q * GPITCH + cpair * 2] = val;
        }
    }
    __syncthreads();

    // ---- stage 2: H = G @ P1w via MFMA; fused relu + dot(P2w) ----
    int w = t >> 6, lane = t & 63;
    int mtile = w >> 1;            // 0/1 -> rows 0-15 / 16-31
    int nhalf = w & 1;             // 0/1 -> n-tiles 0-7 / 8-15
    int quad = lane >> 4, lcol = lane & 15;

    frag_cd acc[8];
    #pragma unroll
    for (int n = 0; n < 8; ++n) acc[n] = (frag_cd){0.f, 0.f, 0.f, 0.f};

    const frag_ab* bp = (const frag_ab*)Bpack;
    for (int kt = 0; kt < 8; ++kt) {
        frag_ab a = *(const frag_ab*)&Gs[(mtile * 16 + lcol) * GPITCH + kt * 32 + quad * 8];
        #pragma unroll
        for (int n = 0; n < 8; ++n) {
            frag_ab b = bp[((nhalf * 8 + n) * 8 + kt) * 64 + lane];
            acc[n] = __builtin_amdgcn_mfma_f32_16x16x32_bf16(a, b, acc[n], 0, 0, 0);
        }
    }

    // epilogue: per-lane partial of relu(H+b1) . P2w over this wave's 8 n-tiles
    float part[4] = {0.f, 0.f, 0.f, 0.f};
    #pragma unroll
    for (int n = 0; n < 8; ++n) {
        int col = (nhalf * 8 + n) * 16 + lcol;
        float bb = P1b[col];
        float pw = P2w[col];
        #pragma unroll
        for (int r = 0; r < 4; ++r) {
            float vv = fmaxf(acc[n][r] + bb, 0.f);
            part[r] = fmaf(vv, pw, part[r]);
        }
    }
    // reduce across the 16 lanes (lcol 0..15) sharing each row
    #pragma unroll
    for (int r = 0; r < 4; ++r) {
        float s = part[r];
        s += __shfl_down(s, 8);
        s += __shfl_down(s, 4);
        s += __shfl_down(s, 2);
        s += __shfl_down(s, 1);
        part[r] = s;
    }
    if (lcol == 0) {
        #pragma unroll
        for (int r = 0; r < 4; ++r)
            red[nhalf][mtile * 16 + quad * 4 + r] = part[r];
    }
    __syncthreads();

    if (t < 32) {
        int qq = q0 + t;
        if (qq < Q) {
            float s = red[0][t] + red[1][t] + P2b[0];
            out[qq] = 1.0f / (1.0f + expf(-s));
        }
    }
}

extern "C" void kernel_launch(void* const* d_in, const int* in_sizes, int n_in,
                              void* d_out, int out_size, void* d_ws, size_t ws_size,
                              hipStream_t stream) {
    const int*   edge_index = (const int*)d_in[0];
    const int*   edges      = (const int*)d_in[1];
    const float* emb        = (const float*)d_in[2];
    const float* W1         = (const float*)d_in[3];
    const float* b1         = (const float*)d_in[4];
    const float* W2         = (const float*)d_in[5];
    const float* b2         = (const float*)d_in[6];
    const float* P1w        = (const float*)d_in[7];
    const float* P1b        = (const float*)d_in[8];
    const float* P2w        = (const float*)d_in[9];
    const float* P2b        = (const float*)d_in[10];

    int E  = in_sizes[0] / 2;
    int Q  = in_sizes[1] / 2;
    int Nn = in_sizes[2] / D;

    const int* rowp = edge_index;
    const int* colp = edge_index + E;
    const int* uq   = edges;
    const int* vq   = edges + Q;
    float* out = (float*)d_out;

    // ---- workspace layout ----
    char* ws = (char*)d_ws;
    size_t off = 0;
    auto alloc = [&](size_t bytes) -> char* {
        char* p = ws + off;
        off = (off + bytes + 255) & ~(size_t)255;
        return p;
    };
    float*          dinv   = (float*)alloc((size_t)Nn * 4);
    int*            rowptr = (int*)  alloc(((size_t)Nn + 1) * 4);
    int*            ebuf   = (int*)  alloc((size_t)E * 4);
    unsigned short* Bpack  = (unsigned short*)alloc(65536 * 2);
    float*          hbuf   = (float*)alloc((size_t)Nn * D * 4);
    float*          xbuf   = (float*)alloc((size_t)Nn * D * 4);

    // aliases into xbuf (dead regions at time of use):
    //  - CSR temporaries: used before conv1 writes xbuf
    int* degi  = (int*)xbuf;
    int* fill  = degi + Nn;
    int* bsums = degi + 2 * Nn;
    //  - X16 (bf16 conv2 output): xbuf is dead after gemm2 reads it
    unsigned short* X16 = (unsigned short*)xbuf;

    int nb;
    int nscan = (Nn + SCAN_CHUNK - 1) / SCAN_CHUNK;

    // CSR build
    nb = (2 * Nn + 255) / 256; k_zero_int<<<nb, 256, 0, stream>>>(degi, 2 * Nn);
    nb = (E + 255) / 256;      k_count_int<<<nb, 256, 0, stream>>>(rowp, degi, E);
    k_scan_block<<<nscan, 256, 0, stream>>>(degi, rowptr, bsums, Nn);
    k_scan_bsums<<<1, 256, 0, stream>>>(bsums, nscan);
    nb = (Nn + 255) / 256;     k_scan_add<<<nb, 256, 0, stream>>>(rowptr, bsums, Nn, E);
    nb = (Nn + 255) / 256;     k_dinv<<<nb, 256, 0, stream>>>(degi, dinv, Nn);
    nb = (E + 255) / 256;      k_bucket<<<nb, 256, 0, stream>>>(rowp, colp, rowptr, fill, ebuf, E);

    // pack P1w for MFMA B operand
    k_packB<<<256, 256, 0, stream>>>(P1w, Bpack);

    // conv1: h = emb @ W1 ; x1 = relu(norm-agg(h) + b1)   [fp32]
    nb = (Nn + 31) / 32; k_gemm<<<nb, 256, 0, stream>>>(emb, W1, hbuf, Nn);
    nb = (Nn + 3) / 4;   k_agg<<<nb, 256, 0, stream>>>(hbuf, rowptr, ebuf, dinv, b1, (void*)xbuf, Nn, 1);

    // conv2: h = x1 @ W2 ; x2 = norm-agg(h) + b2          [bf16 out -> X16, aliases xbuf]
    nb = (Nn + 31) / 32; k_gemm<<<nb, 256, 0, stream>>>(xbuf, W2, hbuf, Nn);
    nb = (Nn + 3) / 4;   k_agg<<<nb, 256, 0, stream>>>(hbuf, rowptr, ebuf, dinv, b2, (void*)X16, Nn, 2);

    // link predictor (MFMA bf16)
    nb = (Q + 31) / 32;  k_linkpred<<<nb, 256, 0, stream>>>(uq, vq, X16, Bpack, P1b, P2w, P2b, out, Q);
}

// Round 5
// 513.734 us; speedup vs baseline: 11.8559x; 1.4070x over previous
//
#include <hip/hip_runtime.h>
#include <math.h>

#define D 256
#define SCAN_CHUNK 1024
#define GPITCH 264   // bf16 LDS row pitch (pad 8) — SQ_LDS_BANK_CONFLICT=0 verified r3/r4

typedef __attribute__((ext_vector_type(8))) short frag_ab;   // 8 bf16
typedef __attribute__((ext_vector_type(4))) float frag_cd;   // 4 fp32

__device__ inline unsigned short f2b(float f) {
    unsigned int u = __float_as_uint(f);
    u += 0x7fffu + ((u >> 16) & 1u);
    return (unsigned short)(u >> 16);
}
__device__ inline float b2f(unsigned short h) {
    return __uint_as_float(((unsigned int)h) << 16);
}

// ---------- zero int buffer ----------
__global__ void k_zero_int(int* p, int n) {
    int i = blockIdx.x * 256 + threadIdx.x;
    if (i < n) p[i] = 0;
}

// ---------- int degree count ----------
__global__ void k_count_int(const int* __restrict__ row, int* deg, int E) {
    int e = blockIdx.x * 256 + threadIdx.x;
    if (e < E) atomicAdd(&deg[row[e]], 1);
}

// ---------- prefix scan (3 stages); excl written into rowptr ----------
__global__ __launch_bounds__(256) void k_scan_block(const int* __restrict__ deg, int* __restrict__ excl,
                                                    int* __restrict__ bsums, int n) {
    __shared__ int s[256];
    int blk = blockIdx.x, t = threadIdx.x;
    int base = blk * SCAN_CHUNK + t * 4;
    int v0 = (base + 0 < n) ? deg[base + 0] : 0;
    int v1 = (base + 1 < n) ? deg[base + 1] : 0;
    int v2 = (base + 2 < n) ? deg[base + 2] : 0;
    int v3 = (base + 3 < n) ? deg[base + 3] : 0;
    int tsum = v0 + v1 + v2 + v3;
    s[t] = tsum;
    __syncthreads();
    for (int off = 1; off < 256; off <<= 1) {
        int x = (t >= off) ? s[t - off] : 0;
        __syncthreads();
        s[t] += x;
        __syncthreads();
    }
    int run = s[t] - tsum;
    if (t == 255) bsums[blk] = s[255];
    if (base + 0 < n) excl[base + 0] = run;
    run += v0;
    if (base + 1 < n) excl[base + 1] = run;
    run += v1;
    if (base + 2 < n) excl[base + 2] = run;
    run += v2;
    if (base + 3 < n) excl[base + 3] = run;
}

__global__ __launch_bounds__(256) void k_scan_bsums(int* bsums, int nb) {
    __shared__ int s[256];
    int t = threadIdx.x;
    int v = (t < nb) ? bsums[t] : 0;
    s[t] = v;
    __syncthreads();
    for (int off = 1; off < 256; off <<= 1) {
        int x = (t >= off) ? s[t - off] : 0;
        __syncthreads();
        s[t] += x;
        __syncthreads();
    }
    if (t < nb) bsums[t] = s[t] - v;
}

__global__ void k_scan_add(int* __restrict__ rowptr, const int* __restrict__ bsums, int n, int total) {
    int i = blockIdx.x * 256 + threadIdx.x;
    if (i < n) rowptr[i] += bsums[i / SCAN_CHUNK];
    if (i == 0) rowptr[n] = total;
}

// ---------- dinv = (deg+1)^-1/2 ----------
__global__ void k_dinv(const int* __restrict__ deg, float* __restrict__ dinv, int n) {
    int i = blockIdx.x * 256 + threadIdx.x;
    if (i < n) dinv[i] = rsqrtf((float)(deg[i] + 1));
}

// ---------- bucket edges into CSR ----------
__global__ void k_bucket(const int* __restrict__ row, const int* __restrict__ col,
                         const int* __restrict__ rowptr, int* __restrict__ fill,
                         int* __restrict__ ebuf, int E) {
    int e = blockIdx.x * 256 + threadIdx.x;
    if (e >= E) return;
    int r = row[e];
    int pos = atomicAdd(&fill[r], 1);
    ebuf[rowptr[r] + pos] = col[e];
}

// ---------- pack fp32 [k][n] weight into MFMA B-fragment order (bf16) ----------
// frag f = (ntile*8 + kt)*64 + lane ; elem j -> B[k = kt*32 + (lane>>4)*8 + j][n = ntile*16 + (lane&15)]
__global__ void k_packB(const float* __restrict__ W, unsigned short* __restrict__ Bp) {
    int i = blockIdx.x * 256 + threadIdx.x;   // 65536 total
    int ntile = i >> 12;
    int kt = (i >> 9) & 7;
    int lane = (i >> 3) & 63;
    int j = i & 7;
    int k = kt * 32 + (lane >> 4) * 8 + j;
    int n = ntile * 16 + (lane & 15);
    Bp[i] = f2b(W[k * D + n]);
}

// ---------- MFMA GEMM: H16[nrows,256] = X[nrows,256] @ W  (bf16 in/out, fp32 acc) ----------
// xIsF32: A source is fp32 (converted during staging) else bf16.
__global__ __launch_bounds__(256) void k_gemm_mfma(const void* __restrict__ X, int xIsF32,
                                                   const unsigned short* __restrict__ Bpack,
                                                   unsigned short* __restrict__ H, int nrows) {
    __shared__ unsigned short As[32 * GPITCH];
    int t = threadIdx.x;
    int rowBase = blockIdx.x * 32;

    // stage A tile (32 x 256 bf16)
    {
        int half = t >> 7;          // which row of the pair
        int cpair = t & 127;        // uint (2 bf16) within the row
        for (int qi = 0; qi < 32; qi += 2) {
            int q = qi + half;
            int r = rowBase + q;
            unsigned int val = 0;
            if (r < nrows) {
                if (xIsF32) {
                    const float* xr = (const float*)X + (size_t)r * D + cpair * 2;
                    val = (unsigned int)f2b(xr[0]) | ((unsigned int)f2b(xr[1]) << 16);
                } else {
                    val = ((const unsigned int*)((const unsigned short*)X + (size_t)r * D))[cpair];
                }
            }
            *(unsigned int*)&As[q * GPITCH + cpair * 2] = val;
        }
    }
    __syncthreads();

    int w = t >> 6, lane = t & 63;
    int mtile = w >> 1;             // 0/1: rows 0-15 / 16-31
    int nhalf = w & 1;              // 0/1: cols 0-127 / 128-255
    int quad = lane >> 4, lcol = lane & 15;

    frag_cd acc[8];
    #pragma unroll
    for (int n = 0; n < 8; ++n) acc[n] = (frag_cd){0.f, 0.f, 0.f, 0.f};

    const frag_ab* bp = (const frag_ab*)Bpack;
    for (int kt = 0; kt < 8; ++kt) {
        frag_ab a = *(const frag_ab*)&As[(mtile * 16 + lcol) * GPITCH + kt * 32 + quad * 8];
        #pragma unroll
        for (int n = 0; n < 8; ++n) {
            frag_ab b = bp[((nhalf * 8 + n) * 8 + kt) * 64 + lane];
            acc[n] = __builtin_amdgcn_mfma_f32_16x16x32_bf16(a, b, acc[n], 0, 0, 0);
        }
    }

    // C/D layout (verified r3/r4): col = lcol (within ntile), row = quad*4 + reg
    #pragma unroll
    for (int n = 0; n < 8; ++n) {
        int col = (nhalf * 8 + n) * 16 + lcol;
        #pragma unroll
        for (int r = 0; r < 4; ++r) {
            int row = rowBase + mtile * 16 + quad * 4 + r;
            if (row < nrows) H[(size_t)row * D + col] = f2b(acc[n][r]);
        }
    }
}

// ---------- aggregate by gather (bf16 rows): one wave per destination node ----------
__global__ __launch_bounds__(256) void k_agg(const unsigned short* __restrict__ Hh,
                                             const int* __restrict__ rowptr, const int* __restrict__ ebuf,
                                             const float* __restrict__ dinv, const float* __restrict__ b,
                                             unsigned short* __restrict__ Xo, int n, int relu) {
    int node = blockIdx.x * 4 + (threadIdx.x >> 6);
    if (node >= n) return;
    int lane = threadIdx.x & 63;
    int c4 = lane * 4;

    float dn = dinv[node];
    float self = dn * dn;

    uint2 hp = *(const uint2*)&Hh[(size_t)node * D + c4];
    float4 bb = *(const float4*)&b[c4];
    float a0 = fmaf(b2f((unsigned short)(hp.x & 0xffffu)), self, bb.x);
    float a1 = fmaf(b2f((unsigned short)(hp.x >> 16)),     self, bb.y);
    float a2 = fmaf(b2f((unsigned short)(hp.y & 0xffffu)), self, bb.z);
    float a3 = fmaf(b2f((unsigned short)(hp.y >> 16)),     self, bb.w);

    int beg = rowptr[node], end = rowptr[node + 1];
    int j = beg;
    for (; j + 1 < end; j += 2) {
        int cA = ebuf[j], cB = ebuf[j + 1];
        float nA = dn * dinv[cA], nB = dn * dinv[cB];
        uint2 pA = *(const uint2*)&Hh[(size_t)cA * D + c4];
        uint2 pB = *(const uint2*)&Hh[(size_t)cB * D + c4];
        a0 = fmaf(b2f((unsigned short)(pA.x & 0xffffu)), nA, a0);
        a1 = fmaf(b2f((unsigned short)(pA.x >> 16)),     nA, a1);
        a2 = fmaf(b2f((unsigned short)(pA.y & 0xffffu)), nA, a2);
        a3 = fmaf(b2f((unsigned short)(pA.y >> 16)),     nA, a3);
        a0 = fmaf(b2f((unsigned short)(pB.x & 0xffffu)), nB, a0);
        a1 = fmaf(b2f((unsigned short)(pB.x >> 16)),     nB, a1);
        a2 = fmaf(b2f((unsigned short)(pB.y & 0xffffu)), nB, a2);
        a3 = fmaf(b2f((unsigned short)(pB.y >> 16)),     nB, a3);
    }
    if (j < end) {
        int cA = ebuf[j];
        float nA = dn * dinv[cA];
        uint2 pA = *(const uint2*)&Hh[(size_t)cA * D + c4];
        a0 = fmaf(b2f((unsigned short)(pA.x & 0xffffu)), nA, a0);
        a1 = fmaf(b2f((unsigned short)(pA.x >> 16)),     nA, a1);
        a2 = fmaf(b2f((unsigned short)(pA.y & 0xffffu)), nA, a2);
        a3 = fmaf(b2f((unsigned short)(pA.y >> 16)),     nA, a3);
    }
    if (relu) {
        a0 = fmaxf(a0, 0.f); a1 = fmaxf(a1, 0.f);
        a2 = fmaxf(a2, 0.f); a3 = fmaxf(a3, 0.f);
    }
    uint2 pk;
    pk.x = (unsigned int)f2b(a0) | ((unsigned int)f2b(a1) << 16);
    pk.y = (unsigned int)f2b(a2) | ((unsigned int)f2b(a3) << 16);
    *(uint2*)&Xo[(size_t)node * D + c4] = pk;
}

// ---------- link predictor: 32 queries/block, MFMA bf16 ----------
__global__ __launch_bounds__(256) void k_linkpred(const int* __restrict__ u, const int* __restrict__ v,
                                                  const unsigned short* __restrict__ X16,
                                                  const unsigned short* __restrict__ Bpack,
                                                  const float* __restrict__ P1b,
                                                  const float* __restrict__ P2w, const float* __restrict__ P2b,
                                                  float* __restrict__ out, int Q) {
    __shared__ unsigned short Gs[32 * GPITCH];
    __shared__ float red[2][32];

    int t = threadIdx.x;
    int q0 = blockIdx.x * 32;

    // stage 1: gather endpoint rows, elementwise product, bf16 to LDS
    {
        int half = t >> 7;
        int cpair = t & 127;
        for (int qi = 0; qi < 32; qi += 2) {
            int q = qi + half;
            int qq = q0 + q;
            unsigned int val = 0;
            if (qq < Q) {
                const unsigned int* ru = (const unsigned int*)(X16 + (size_t)u[qq] * D);
                const unsigned int* rv = (const unsigned int*)(X16 + (size_t)v[qq] * D);
                unsigned int a = ru[cpair], b = rv[cpair];
                float p0 = b2f((unsigned short)(a & 0xffffu)) * b2f((unsigned short)(b & 0xffffu));
                float p1 = b2f((unsigned short)(a >> 16))     * b2f((unsigned short)(b >> 16));
                val = (unsigned int)f2b(p0) | ((unsigned int)f2b(p1) << 16);
            }
            *(unsigned int*)&Gs[q * GPITCH + cpair * 2] = val;
        }
    }
    __syncthreads();

    // stage 2: H = G @ P1w via MFMA; fused relu + dot(P2w)
    int w = t >> 6, lane = t & 63;
    int mtile = w >> 1;
    int nhalf = w & 1;
    int quad = lane >> 4, lcol = lane & 15;

    frag_cd acc[8];
    #pragma unroll
    for (int n = 0; n < 8; ++n) acc[n] = (frag_cd){0.f, 0.f, 0.f, 0.f};

    const frag_ab* bp = (const frag_ab*)Bpack;
    for (int kt = 0; kt < 8; ++kt) {
        frag_ab a = *(const frag_ab*)&Gs[(mtile * 16 + lcol) * GPITCH + kt * 32 + quad * 8];
        #pragma unroll
        for (int n = 0; n < 8; ++n) {
            frag_ab b = bp[((nhalf * 8 + n) * 8 + kt) * 64 + lane];
            acc[n] = __builtin_amdgcn_mfma_f32_16x16x32_bf16(a, b, acc[n], 0, 0, 0);
        }
    }

    float part[4] = {0.f, 0.f, 0.f, 0.f};
    #pragma unroll
    for (int n = 0; n < 8; ++n) {
        int col = (nhalf * 8 + n) * 16 + lcol;
        float bb = P1b[col];
        float pw = P2w[col];
        #pragma unroll
        for (int r = 0; r < 4; ++r) {
            float vv = fmaxf(acc[n][r] + bb, 0.f);
            part[r] = fmaf(vv, pw, part[r]);
        }
    }
    #pragma unroll
    for (int r = 0; r < 4; ++r) {
        float s = part[r];
        s += __shfl_down(s, 8);
        s += __shfl_down(s, 4);
        s += __shfl_down(s, 2);
        s += __shfl_down(s, 1);
        part[r] = s;
    }
    if (lcol == 0) {
        #pragma unroll
        for (int r = 0; r < 4; ++r)
            red[nhalf][mtile * 16 + quad * 4 + r] = part[r];
    }
    __syncthreads();

    if (t < 32) {
        int qq = q0 + t;
        if (qq < Q) {
            float s = red[0][t] + red[1][t] + P2b[0];
            out[qq] = 1.0f / (1.0f + expf(-s));
        }
    }
}

extern "C" void kernel_launch(void* const* d_in, const int* in_sizes, int n_in,
                              void* d_out, int out_size, void* d_ws, size_t ws_size,
                              hipStream_t stream) {
    const int*   edge_index = (const int*)d_in[0];
    const int*   edges      = (const int*)d_in[1];
    const float* emb        = (const float*)d_in[2];
    const float* W1         = (const float*)d_in[3];
    const float* b1         = (const float*)d_in[4];
    const float* W2         = (const float*)d_in[5];
    const float* b2         = (const float*)d_in[6];
    const float* P1w        = (const float*)d_in[7];
    const float* P1b        = (const float*)d_in[8];
    const float* P2w        = (const float*)d_in[9];
    const float* P2b        = (const float*)d_in[10];

    int E  = in_sizes[0] / 2;
    int Q  = in_sizes[1] / 2;
    int Nn = in_sizes[2] / D;

    const int* rowp = edge_index;
    const int* colp = edge_index + E;
    const int* uq   = edges;
    const int* vq   = edges + Q;
    float* out = (float*)d_out;

    // ---- workspace layout ----
    char* ws = (char*)d_ws;
    size_t off = 0;
    auto alloc = [&](size_t bytes) -> char* {
        char* p = ws + off;
        off = (off + bytes + 255) & ~(size_t)255;
        return p;
    };
    float*          dinv   = (float*)alloc((size_t)Nn * 4);
    int*            rowptr = (int*)  alloc(((size_t)Nn + 1) * 4);
    int*            ebuf   = (int*)  alloc((size_t)E * 4);
    unsigned short* BpW1   = (unsigned short*)alloc(65536 * 2);
    unsigned short* BpW2   = (unsigned short*)alloc(65536 * 2);
    unsigned short* BpP1   = (unsigned short*)alloc(65536 * 2);
    unsigned short* hbuf   = (unsigned short*)alloc((size_t)Nn * D * 2);  // bf16
    unsigned short* xbuf   = (unsigned short*)alloc((size_t)Nn * D * 2);  // bf16

    // CSR temporaries aliased into xbuf (dead until first k_agg writes it)
    int* degi  = (int*)xbuf;
    int* fill  = degi + Nn;
    int* bsums = degi + 2 * Nn;

    int nb;
    int nscan = (Nn + SCAN_CHUNK - 1) / SCAN_CHUNK;

    // CSR build
    nb = (2 * Nn + 255) / 256; k_zero_int<<<nb, 256, 0, stream>>>(degi, 2 * Nn);
    nb = (E + 255) / 256;      k_count_int<<<nb, 256, 0, stream>>>(rowp, degi, E);
    k_scan_block<<<nscan, 256, 0, stream>>>(degi, rowptr, bsums, Nn);
    k_scan_bsums<<<1, 256, 0, stream>>>(bsums, nscan);
    nb = (Nn + 255) / 256;     k_scan_add<<<nb, 256, 0, stream>>>(rowptr, bsums, Nn, E);
    nb = (Nn + 255) / 256;     k_dinv<<<nb, 256, 0, stream>>>(degi, dinv, Nn);
    nb = (E + 255) / 256;      k_bucket<<<nb, 256, 0, stream>>>(rowp, colp, rowptr, fill, ebuf, E);

    // pack weights for MFMA B operand
    k_packB<<<256, 256, 0, stream>>>(W1, BpW1);
    k_packB<<<256, 256, 0, stream>>>(W2, BpW2);
    k_packB<<<256, 256, 0, stream>>>(P1w, BpP1);

    // conv1: h = emb @ W1 (MFMA, fp32 A) ; x1 = relu(norm-agg(h) + b1)  [bf16]
    nb = (Nn + 31) / 32; k_gemm_mfma<<<nb, 256, 0, stream>>>((const void*)emb, 1, BpW1, hbuf, Nn);
    nb = (Nn + 3) / 4;   k_agg<<<nb, 256, 0, stream>>>(hbuf, rowptr, ebuf, dinv, b1, xbuf, Nn, 1);

    // conv2: h = x1 @ W2 (MFMA, bf16 A) ; x2 = norm-agg(h) + b2          [bf16]
    nb = (Nn + 31) / 32; k_gemm_mfma<<<nb, 256, 0, stream>>>((const void*)xbuf, 0, BpW2, hbuf, Nn);
    nb = (Nn + 3) / 4;   k_agg<<<nb, 256, 0, stream>>>(hbuf, rowptr, ebuf, dinv, b2, xbuf, Nn, 0);

    // link predictor (MFMA bf16)
    nb = (Q + 31) / 32;  k_linkpred<<<nb, 256, 0, stream>>>(uq, vq, xbuf, BpP1, P1b, P2w, P2b, out, Q);
}

// Round 6
// 470.004 us; speedup vs baseline: 12.9590x; 1.0930x over previous
//
#include <hip/hip_runtime.h>
#include <math.h>

#define D 256
#define SCAN_CHUNK 1024
#define GPITCH 264   // bf16 LDS row pitch (pad 8) — conflict-free MFMA A-reads (r3-r5)

typedef __attribute__((ext_vector_type(8))) short frag_ab;   // 8 bf16
typedef __attribute__((ext_vector_type(4))) float frag_cd;   // 4 fp32

__device__ inline unsigned short f2b(float f) {
    unsigned int u = __float_as_uint(f);
    u += 0x7fffu + ((u >> 16) & 1u);
    return (unsigned short)(u >> 16);
}
__device__ inline float b2f(unsigned short h) {
    return __uint_as_float(((unsigned int)h) << 16);
}

// async global->LDS, 16B per lane; LDS dest = wave-uniform base + lane*16
__device__ inline void async_ld16(const void* g, void* l) {
    __builtin_amdgcn_global_load_lds(
        (const __attribute__((address_space(1))) void*)g,
        (__attribute__((address_space(3))) void*)l,
        16, 0, 0);
}

// ---------- zero int buffer ----------
__global__ void k_zero_int(int* p, int n) {
    int i = blockIdx.x * 256 + threadIdx.x;
    if (i < n) p[i] = 0;
}

// ---------- int degree count ----------
__global__ void k_count_int(const int* __restrict__ row, int* deg, int E) {
    int e = blockIdx.x * 256 + threadIdx.x;
    if (e < E) atomicAdd(&deg[row[e]], 1);
}

// ---------- prefix scan (3 stages); excl written into rowptr ----------
__global__ __launch_bounds__(256) void k_scan_block(const int* __restrict__ deg, int* __restrict__ excl,
                                                    int* __restrict__ bsums, int n) {
    __shared__ int s[256];
    int blk = blockIdx.x, t = threadIdx.x;
    int base = blk * SCAN_CHUNK + t * 4;
    int v0 = (base + 0 < n) ? deg[base + 0] : 0;
    int v1 = (base + 1 < n) ? deg[base + 1] : 0;
    int v2 = (base + 2 < n) ? deg[base + 2] : 0;
    int v3 = (base + 3 < n) ? deg[base + 3] : 0;
    int tsum = v0 + v1 + v2 + v3;
    s[t] = tsum;
    __syncthreads();
    for (int off = 1; off < 256; off <<= 1) {
        int x = (t >= off) ? s[t - off] : 0;
        __syncthreads();
        s[t] += x;
        __syncthreads();
    }
    int run = s[t] - tsum;
    if (t == 255) bsums[blk] = s[255];
    if (base + 0 < n) excl[base + 0] = run;
    run += v0;
    if (base + 1 < n) excl[base + 1] = run;
    run += v1;
    if (base + 2 < n) excl[base + 2] = run;
    run += v2;
    if (base + 3 < n) excl[base + 3] = run;
}

__global__ __launch_bounds__(256) void k_scan_bsums(int* bsums, int nb) {
    __shared__ int s[256];
    int t = threadIdx.x;
    int v = (t < nb) ? bsums[t] : 0;
    s[t] = v;
    __syncthreads();
    for (int off = 1; off < 256; off <<= 1) {
        int x = (t >= off) ? s[t - off] : 0;
        __syncthreads();
        s[t] += x;
        __syncthreads();
    }
    if (t < nb) bsums[t] = s[t] - v;
}

__global__ void k_scan_add(int* __restrict__ rowptr, const int* __restrict__ bsums, int n, int total) {
    int i = blockIdx.x * 256 + threadIdx.x;
    if (i < n) rowptr[i] += bsums[i / SCAN_CHUNK];
    if (i == 0) rowptr[n] = total;
}

// ---------- dinv = (deg+1)^-1/2 ----------
__global__ void k_dinv(const int* __restrict__ deg, float* __restrict__ dinv, int n) {
    int i = blockIdx.x * 256 + threadIdx.x;
    if (i < n) dinv[i] = rsqrtf((float)(deg[i] + 1));
}

// ---------- bucket edges into CSR ----------
__global__ void k_bucket(const int* __restrict__ row, const int* __restrict__ col,
                         const int* __restrict__ rowptr, int* __restrict__ fill,
                         int* __restrict__ ebuf, int E) {
    int e = blockIdx.x * 256 + threadIdx.x;
    if (e >= E) return;
    int r = row[e];
    int pos = atomicAdd(&fill[r], 1);
    ebuf[rowptr[r] + pos] = col[e];
}

// ---------- pack fp32 [k][n] weight into MFMA B-fragment order (bf16) ----------
__global__ void k_packB(const float* __restrict__ W, unsigned short* __restrict__ Bp) {
    int i = blockIdx.x * 256 + threadIdx.x;   // 65536 total
    int ntile = i >> 12;
    int kt = (i >> 9) & 7;
    int lane = (i >> 3) & 63;
    int j = i & 7;
    int k = kt * 32 + (lane >> 4) * 8 + j;
    int n = ntile * 16 + (lane & 15);
    Bp[i] = f2b(W[k * D + n]);
}

// ---------- MFMA GEMM: H16[nrows,256] = X[nrows,256] @ W  (bf16 in/out, fp32 acc) ----------
__global__ __launch_bounds__(256) void k_gemm_mfma(const void* __restrict__ X, int xIsF32,
                                                   const unsigned short* __restrict__ Bpack,
                                                   unsigned short* __restrict__ H, int nrows) {
    __shared__ unsigned short As[32 * GPITCH];
    int t = threadIdx.x;
    int rowBase = blockIdx.x * 32;

    {
        int half = t >> 7;
        int cpair = t & 127;
        for (int qi = 0; qi < 32; qi += 2) {
            int q = qi + half;
            int r = rowBase + q;
            unsigned int val = 0;
            if (r < nrows) {
                if (xIsF32) {
                    const float* xr = (const float*)X + (size_t)r * D + cpair * 2;
                    val = (unsigned int)f2b(xr[0]) | ((unsigned int)f2b(xr[1]) << 16);
                } else {
                    val = ((const unsigned int*)((const unsigned short*)X + (size_t)r * D))[cpair];
                }
            }
            *(unsigned int*)&As[q * GPITCH + cpair * 2] = val;
        }
    }
    __syncthreads();

    int w = t >> 6, lane = t & 63;
    int mtile = w >> 1;
    int nhalf = w & 1;
    int quad = lane >> 4, lcol = lane & 15;

    frag_cd acc[8];
    #pragma unroll
    for (int n = 0; n < 8; ++n) acc[n] = (frag_cd){0.f, 0.f, 0.f, 0.f};

    const frag_ab* bp = (const frag_ab*)Bpack;
    for (int kt = 0; kt < 8; ++kt) {
        frag_ab a = *(const frag_ab*)&As[(mtile * 16 + lcol) * GPITCH + kt * 32 + quad * 8];
        #pragma unroll
        for (int n = 0; n < 8; ++n) {
            frag_ab b = bp[((nhalf * 8 + n) * 8 + kt) * 64 + lane];
            acc[n] = __builtin_amdgcn_mfma_f32_16x16x32_bf16(a, b, acc[n], 0, 0, 0);
        }
    }

    #pragma unroll
    for (int n = 0; n < 8; ++n) {
        int col = (nhalf * 8 + n) * 16 + lcol;
        #pragma unroll
        for (int r = 0; r < 4; ++r) {
            int row = rowBase + mtile * 16 + quad * 4 + r;
            if (row < nrows) H[(size_t)row * D + col] = f2b(acc[n][r]);
        }
    }
}

// ---------- aggregate by gather (bf16 rows): one wave per destination node ----------
__device__ inline void acc_row(const unsigned short* Hh, int c, float nw, int c4,
                               float& a0, float& a1, float& a2, float& a3) {
    uint2 p = *(const uint2*)&Hh[(size_t)c * D + c4];
    a0 = fmaf(b2f((unsigned short)(p.x & 0xffffu)), nw, a0);
    a1 = fmaf(b2f((unsigned short)(p.x >> 16)),     nw, a1);
    a2 = fmaf(b2f((unsigned short)(p.y & 0xffffu)), nw, a2);
    a3 = fmaf(b2f((unsigned short)(p.y >> 16)),     nw, a3);
}

__global__ __launch_bounds__(256) void k_agg(const unsigned short* __restrict__ Hh,
                                             const int* __restrict__ rowptr, const int* __restrict__ ebuf,
                                             const float* __restrict__ dinv, const float* __restrict__ b,
                                             unsigned short* __restrict__ Xo, int n, int relu) {
    int node = blockIdx.x * 4 + (threadIdx.x >> 6);
    if (node >= n) return;
    int lane = threadIdx.x & 63;
    int c4 = lane * 4;

    float dn = dinv[node];
    float self = dn * dn;

    uint2 hp = *(const uint2*)&Hh[(size_t)node * D + c4];
    float4 bb = *(const float4*)&b[c4];
    float a0 = fmaf(b2f((unsigned short)(hp.x & 0xffffu)), self, bb.x);
    float a1 = fmaf(b2f((unsigned short)(hp.x >> 16)),     self, bb.y);
    float a2 = fmaf(b2f((unsigned short)(hp.y & 0xffffu)), self, bb.z);
    float a3 = fmaf(b2f((unsigned short)(hp.y >> 16)),     self, bb.w);

    int beg = rowptr[node], end = rowptr[node + 1];
    int j = beg;
    for (; j + 3 < end; j += 4) {
        int cA = ebuf[j], cB = ebuf[j + 1], cC = ebuf[j + 2], cD = ebuf[j + 3];
        float nA = dn * dinv[cA], nB = dn * dinv[cB], nC = dn * dinv[cC], nD = dn * dinv[cD];
        acc_row(Hh, cA, nA, c4, a0, a1, a2, a3);
        acc_row(Hh, cB, nB, c4, a0, a1, a2, a3);
        acc_row(Hh, cC, nC, c4, a0, a1, a2, a3);
        acc_row(Hh, cD, nD, c4, a0, a1, a2, a3);
    }
    for (; j < end; ++j) {
        int cA = ebuf[j];
        acc_row(Hh, cA, dn * dinv[cA], c4, a0, a1, a2, a3);
    }
    if (relu) {
        a0 = fmaxf(a0, 0.f); a1 = fmaxf(a1, 0.f);
        a2 = fmaxf(a2, 0.f); a3 = fmaxf(a3, 0.f);
    }
    uint2 pk;
    pk.x = (unsigned int)f2b(a0) | ((unsigned int)f2b(a1) << 16);
    pk.y = (unsigned int)f2b(a2) | ((unsigned int)f2b(a3) << 16);
    *(uint2*)&Xo[(size_t)node * D + c4] = pk;
}

// ---------- link predictor: 32 queries/block, async UV staging + MFMA ----------
__global__ __launch_bounds__(256) void k_linkpred(const int* __restrict__ u, const int* __restrict__ v,
                                                  const unsigned short* __restrict__ X16,
                                                  const unsigned short* __restrict__ Bpack,
                                                  const float* __restrict__ P1b,
                                                  const float* __restrict__ P2w, const float* __restrict__ P2b,
                                                  float* __restrict__ out, int Q) {
    __shared__ unsigned short UV[32 * 512];      // per q: 256 bf16 u-row | 256 bf16 v-row (1 KB)
    __shared__ unsigned short Gs[32 * GPITCH];   // product tile, padded
    __shared__ float red[4][32];

    int t = threadIdx.x;
    int w = t >> 6, lane = t & 63;
    int q0 = blockIdx.x * 32;

    // ---- stage 0: async gather of endpoint rows (8 q per wave, 16B/lane) ----
    for (int i = 0; i < 8; ++i) {
        int q = w * 8 + i;
        int qq = q0 + q;
        int qc = (qq < Q) ? qq : 0;
        int ua = u[qc], va = v[qc];
        const char* src = (lane < 32)
            ? (const char*)(X16 + (size_t)ua * D) + lane * 16
            : (const char*)(X16 + (size_t)va * D) + (lane - 32) * 16;
        async_ld16(src, (char*)UV + q * 1024 + lane * 16);
    }
    asm volatile("s_waitcnt vmcnt(0)" ::: "memory");
    __syncthreads();

    // ---- stage 1: elementwise product UV -> Gs (bf16) ----
    #pragma unroll
    for (int i = 0; i < 8; ++i) {
        int q = i * 4 + (t >> 6);
        uint2 u2 = *(const uint2*)&UV[q * 512 + lane * 4];
        uint2 v2 = *(const uint2*)&UV[q * 512 + 256 + lane * 4];
        float p0 = b2f((unsigned short)(u2.x & 0xffffu)) * b2f((unsigned short)(v2.x & 0xffffu));
        float p1 = b2f((unsigned short)(u2.x >> 16))     * b2f((unsigned short)(v2.x >> 16));
        float p2 = b2f((unsigned short)(u2.y & 0xffffu)) * b2f((unsigned short)(v2.y & 0xffffu));
        float p3 = b2f((unsigned short)(u2.y >> 16))     * b2f((unsigned short)(v2.y >> 16));
        uint2 pk;
        pk.x = (unsigned int)f2b(p0) | ((unsigned int)f2b(p1) << 16);
        pk.y = (unsigned int)f2b(p2) | ((unsigned int)f2b(p3) << 16);
        *(uint2*)&Gs[q * GPITCH + lane * 4] = pk;
    }
    __syncthreads();

    // ---- stage 2: MFMA — wave w owns ntiles w*4..w*4+3, both mtiles ----
    int quad = lane >> 4, lcol = lane & 15;

    frag_cd acc[2][4];
    #pragma unroll
    for (int m = 0; m < 2; ++m)
        #pragma unroll
        for (int jn = 0; jn < 4; ++jn) acc[m][jn] = (frag_cd){0.f, 0.f, 0.f, 0.f};

    const frag_ab* bp = (const frag_ab*)Bpack;
    for (int kt = 0; kt < 8; ++kt) {
        frag_ab a0 = *(const frag_ab*)&Gs[lcol * GPITCH + kt * 32 + quad * 8];
        frag_ab a1 = *(const frag_ab*)&Gs[(16 + lcol) * GPITCH + kt * 32 + quad * 8];
        #pragma unroll
        for (int jn = 0; jn < 4; ++jn) {
            frag_ab b = bp[((w * 4 + jn) * 8 + kt) * 64 + lane];
            acc[0][jn] = __builtin_amdgcn_mfma_f32_16x16x32_bf16(a0, b, acc[0][jn], 0, 0, 0);
            acc[1][jn] = __builtin_amdgcn_mfma_f32_16x16x32_bf16(a1, b, acc[1][jn], 0, 0, 0);
        }
    }

    // ---- epilogue: relu(H+b1) . P2w, partial over this wave's 4 ntiles ----
    float part[2][4] = {{0.f,0.f,0.f,0.f},{0.f,0.f,0.f,0.f}};
    #pragma unroll
    for (int jn = 0; jn < 4; ++jn) {
        int col = (w * 4 + jn) * 16 + lcol;
        float bb = P1b[col];
        float pw = P2w[col];
        #pragma unroll
        for (int m = 0; m < 2; ++m)
            #pragma unroll
            for (int r = 0; r < 4; ++r)
                part[m][r] = fmaf(fmaxf(acc[m][jn][r] + bb, 0.f), pw, part[m][r]);
    }
    #pragma unroll
    for (int m = 0; m < 2; ++m)
        #pragma unroll
        for (int r = 0; r < 4; ++r) {
            float s = part[m][r];
            s += __shfl_down(s, 8);
            s += __shfl_down(s, 4);
            s += __shfl_down(s, 2);
            s += __shfl_down(s, 1);
            part[m][r] = s;
        }
    if (lcol == 0) {
        #pragma unroll
        for (int m = 0; m < 2; ++m)
            #pragma unroll
            for (int r = 0; r < 4; ++r)
                red[w][m * 16 + quad * 4 + r] = part[m][r];
    }
    __syncthreads();

    if (t < 32) {
        int qq = q0 + t;
        if (qq < Q) {
            float s = red[0][t] + red[1][t] + red[2][t] + red[3][t] + P2b[0];
            out[qq] = 1.0f / (1.0f + expf(-s));
        }
    }
}

extern "C" void kernel_launch(void* const* d_in, const int* in_sizes, int n_in,
                              void* d_out, int out_size, void* d_ws, size_t ws_size,
                              hipStream_t stream) {
    const int*   edge_index = (const int*)d_in[0];
    const int*   edges      = (const int*)d_in[1];
    const float* emb        = (const float*)d_in[2];
    const float* W1         = (const float*)d_in[3];
    const float* b1         = (const float*)d_in[4];
    const float* W2         = (const float*)d_in[5];
    const float* b2         = (const float*)d_in[6];
    const float* P1w        = (const float*)d_in[7];
    const float* P1b        = (const float*)d_in[8];
    const float* P2w        = (const float*)d_in[9];
    const float* P2b        = (const float*)d_in[10];

    int E  = in_sizes[0] / 2;
    int Q  = in_sizes[1] / 2;
    int Nn = in_sizes[2] / D;

    const int* rowp = edge_index;
    const int* colp = edge_index + E;
    const int* uq   = edges;
    const int* vq   = edges + Q;
    float* out = (float*)d_out;

    // ---- workspace layout ----
    char* ws = (char*)d_ws;
    size_t off = 0;
    auto alloc = [&](size_t bytes) -> char* {
        char* p = ws + off;
        off = (off + bytes + 255) & ~(size_t)255;
        return p;
    };
    float*          dinv   = (float*)alloc((size_t)Nn * 4);
    int*            rowptr = (int*)  alloc(((size_t)Nn + 1) * 4);
    int*            ebuf   = (int*)  alloc((size_t)E * 4);
    unsigned short* BpW1   = (unsigned short*)alloc(65536 * 2);
    unsigned short* BpW2   = (unsigned short*)alloc(65536 * 2);
    unsigned short* BpP1   = (unsigned short*)alloc(65536 * 2);
    unsigned short* hbuf   = (unsigned short*)alloc((size_t)Nn * D * 2);  // bf16
    unsigned short* xbuf   = (unsigned short*)alloc((size_t)Nn * D * 2);  // bf16

    // CSR temporaries aliased into xbuf (dead until first k_agg writes it)
    int* degi  = (int*)xbuf;
    int* fill  = degi + Nn;
    int* bsums = degi + 2 * Nn;

    int nb;
    int nscan = (Nn + SCAN_CHUNK - 1) / SCAN_CHUNK;

    // CSR build
    nb = (2 * Nn + 255) / 256; k_zero_int<<<nb, 256, 0, stream>>>(degi, 2 * Nn);
    nb = (E + 255) / 256;      k_count_int<<<nb, 256, 0, stream>>>(rowp, degi, E);
    k_scan_block<<<nscan, 256, 0, stream>>>(degi, rowptr, bsums, Nn);
    k_scan_bsums<<<1, 256, 0, stream>>>(bsums, nscan);
    nb = (Nn + 255) / 256;     k_scan_add<<<nb, 256, 0, stream>>>(rowptr, bsums, Nn, E);
    nb = (Nn + 255) / 256;     k_dinv<<<nb, 256, 0, stream>>>(degi, dinv, Nn);
    nb = (E + 255) / 256;      k_bucket<<<nb, 256, 0, stream>>>(rowp, colp, rowptr, fill, ebuf, E);

    // pack weights for MFMA B operand
    k_packB<<<256, 256, 0, stream>>>(W1, BpW1);
    k_packB<<<256, 256, 0, stream>>>(W2, BpW2);
    k_packB<<<256, 256, 0, stream>>>(P1w, BpP1);

    // conv1: h = emb @ W1 (MFMA, fp32 A) ; x1 = relu(norm-agg(h) + b1)  [bf16]
    nb = (Nn + 31) / 32; k_gemm_mfma<<<nb, 256, 0, stream>>>((const void*)emb, 1, BpW1, hbuf, Nn);
    nb = (Nn + 3) / 4;   k_agg<<<nb, 256, 0, stream>>>(hbuf, rowptr, ebuf, dinv, b1, xbuf, Nn, 1);

    // conv2: h = x1 @ W2 (MFMA, bf16 A) ; x2 = norm-agg(h) + b2          [bf16]
    nb = (Nn + 31) / 32; k_gemm_mfma<<<nb, 256, 0, stream>>>((const void*)xbuf, 0, BpW2, hbuf, Nn);
    nb = (Nn + 3) / 4;   k_agg<<<nb, 256, 0, stream>>>(hbuf, rowptr, ebuf, dinv, b2, xbuf, Nn, 0);

    // link predictor (async staging + MFMA bf16)
    nb = (Q + 31) / 32;  k_linkpred<<<nb, 256, 0, stream>>>(uq, vq, xbuf, BpP1, P1b, P2w, P2b, out, Q);
}